// Round 9
// baseline (2329.283 us; speedup 1.0000x reference)
//
#include <hip/hip_runtime.h>
#include <hip/hip_bf16.h>

#define BB 64
#define LL 512
#define DD 256
#define VV 32000
#define KK 6
#define HH 4
#define FF 512
#define MM (BB * LL)

typedef __hip_bfloat16 bf16;
typedef unsigned short ushort_t;
typedef __attribute__((ext_vector_type(8))) __bf16 bf16x8;
typedef __attribute__((ext_vector_type(4))) float f32x4;
#define MFMA __builtin_amdgcn_mfma_f32_16x16x32_bf16

__device__ __forceinline__ ushort_t f2bfbits(float x) {
  return __builtin_bit_cast(unsigned short, (__bf16)x);
}
__device__ __forceinline__ unsigned pkbf(float lo, float hi) {
  return (unsigned)f2bfbits(lo) | ((unsigned)f2bfbits(hi) << 16);
}
union U8 { unsigned u[4]; bf16x8 v; };

// async global->LDS, 16B/lane; dest must be WAVE-UNIFORM base (HW adds lane*16)
__device__ __forceinline__ void gl_lds16(const ushort_t* g, ushort_t* l) {
  __builtin_amdgcn_global_load_lds(
      (const __attribute__((address_space(1))) unsigned int*)g,
      (__attribute__((address_space(3))) unsigned int*)l, 16, 0, 0);
}

__device__ __forceinline__ float blk_sum(float v, float* red) {
  #pragma unroll
  for (int o = 32; o > 0; o >>= 1) v += __shfl_down(v, o, 64);
  __syncthreads();
  if ((threadIdx.x & 63) == 0) red[threadIdx.x >> 6] = v;
  __syncthreads();
  return red[0] + red[1] + red[2] + red[3];
}

__global__ __launch_bounds__(256) void k_lens(const int* __restrict__ tokens, int* __restrict__ lens) {
  __shared__ float red[4];
  int b = blockIdx.x, t = threadIdx.x;
  float c = (tokens[b * LL + t] != 0 ? 1.f : 0.f) + (tokens[b * LL + 256 + t] != 0 ? 1.f : 0.f);
  float s = blk_sum(c, red);
  if (t == 0) lens[b] = (int)(s + 0.5f);
}

__global__ __launch_bounds__(256) void k_embed4(const int* __restrict__ tokens,
                                                const float* __restrict__ tok_emb,
                                                const float* __restrict__ pos_emb,
                                                const float* __restrict__ g,
                                                const float* __restrict__ be,
                                                float* __restrict__ X) {
  int wid = threadIdx.x >> 6, lane = threadIdx.x & 63;
  int row = blockIdx.x * 4 + wid;
  int l = row & (LL - 1);
  int tok = tokens[row];
  float4 a = *reinterpret_cast<const float4*>(tok_emb + (size_t)tok * DD + lane * 4);
  float4 p = *reinterpret_cast<const float4*>(pos_emb + (size_t)l * DD + lane * 4);
  float4 v = {a.x + p.x, a.y + p.y, a.z + p.z, a.w + p.w};
  float s = v.x + v.y + v.z + v.w;
  float q = v.x * v.x + v.y * v.y + v.z * v.z + v.w * v.w;
  #pragma unroll
  for (int o = 32; o > 0; o >>= 1) { s += __shfl_xor(s, o, 64); q += __shfl_xor(q, o, 64); }
  float mu = s * (1.f / DD);
  float rstd = rsqrtf(q * (1.f / DD) - mu * mu + 1e-5f);
  float4 gv = *reinterpret_cast<const float4*>(g + lane * 4);
  float4 bv = *reinterpret_cast<const float4*>(be + lane * 4);
  float4 o4 = {(v.x - mu) * rstd * gv.x + bv.x, (v.y - mu) * rstd * gv.y + bv.y,
               (v.z - mu) * rstd * gv.z + bv.z, (v.w - mu) * rstd * gv.w + bv.w};
  *reinterpret_cast<float4*>(X + (size_t)row * DD + lane * 4) = o4;
}

__global__ __launch_bounds__(256) void k_ln4(const float* __restrict__ X,
                                             const float* __restrict__ g,
                                             const float* __restrict__ be,
                                             const int* __restrict__ lens,
                                             bf16* __restrict__ H) {
  int wid = threadIdx.x >> 6, lane = threadIdx.x & 63;
  int row = blockIdx.x * 4 + wid;
  int b = row >> 9, l = row & (LL - 1);
  if (l >= lens[b]) return;
  float4 v = *reinterpret_cast<const float4*>(X + (size_t)row * DD + lane * 4);
  float s = v.x + v.y + v.z + v.w;
  float q = v.x * v.x + v.y * v.y + v.z * v.z + v.w * v.w;
  #pragma unroll
  for (int o = 32; o > 0; o >>= 1) { s += __shfl_xor(s, o, 64); q += __shfl_xor(q, o, 64); }
  float mu = s * (1.f / DD);
  float rstd = rsqrtf(q * (1.f / DD) - mu * mu + 1e-5f);
  float4 gv = *reinterpret_cast<const float4*>(g + lane * 4);
  float4 bv = *reinterpret_cast<const float4*>(be + lane * 4);
  ushort4 o4;
  o4.x = f2bfbits((v.x - mu) * rstd * gv.x + bv.x);
  o4.y = f2bfbits((v.y - mu) * rstd * gv.y + bv.y);
  o4.z = f2bfbits((v.z - mu) * rstd * gv.z + bv.z);
  o4.w = f2bfbits((v.w - mu) * rstd * gv.w + bv.w);
  *reinterpret_cast<ushort4*>((ushort_t*)H + (size_t)row * DD + lane * 4) = o4;
}

__global__ __launch_bounds__(256) void k_cvtw(const float* __restrict__ w0, const float* __restrict__ w1,
                                              const float* __restrict__ w2, const float* __restrict__ w3,
                                              ushort_t* __restrict__ d) {
  int i = (blockIdx.x * 256 + threadIdx.x) * 4;
  const float* s; int off;
  if (i < 196608)      { s = w0; off = i; }
  else if (i < 262144) { s = w1; off = i - 196608; }
  else if (i < 393216) { s = w2; off = i - 262144; }
  else                 { s = w3; off = i - 393216; }
  float4 v = *reinterpret_cast<const float4*>(s + off);
  ushort4 o;
  o.x = f2bfbits(v.x); o.y = f2bfbits(v.y); o.z = f2bfbits(v.z); o.w = f2bfbits(v.w);
  *reinterpret_cast<ushort4*>(d + i) = o;
}

// -------- wave-stationary GEMM: weights from L2, zero block barriers --------
// Block = 4 waves x 16 rows = 64 m-rows; grid (N/256, M/64). Each wave stages its
// own 16xK A-strip to its private LDS segment (gl_lds, linear dest, src chunk
// pre-swizzled by row), waits vmcnt(0) (per-wave), then loops k: 1 ds_read_b128
// (A frag, reused 16x) + 16 direct-global B frags (L1/L2-hit) + 16 MFMA.
// LDS read slot = (k-chunk ^ (row&7)) -> 2-way per 16-lane group = free.
template <int KD, bool GELU, bool RES, bool OUTBF16>
__global__ __launch_bounds__(256) void k_wgemm(const ushort_t* __restrict__ A,
                                               const ushort_t* __restrict__ Wb,
                                               const float* __restrict__ bias,
                                               const float* __restrict__ res,
                                               void* __restrict__ outp,
                                               const int* __restrict__ lens,
                                               int Ndim) {
  constexpr int C = KD / 8;        // 16B chunks per row
  constexpr int NI = C / 4;        // stage issues per wave (16 rows * C / 64 lanes)
  int m0 = blockIdx.y * 64;
  if ((m0 & (LL - 1)) >= lens[m0 >> 9]) return;   // block-uniform padding skip
  int n0 = blockIdx.x * 256;
  __shared__ __align__(16) ushort_t Al[4][16 * KD];
  int t = threadIdx.x, lane = t & 63, w = t >> 6;
  int fr = lane & 15, fg = lane >> 4;
  ushort_t* Aw = &Al[w][0];
  int mb = m0 + w * 16;

  // stage this wave's 16 rows: LDS[r][c] = A[mb+r][c ^ (r&7)]
  #pragma unroll
  for (int i = 0; i < NI; i++) {
    int d = i * 64 + lane;
    int r = d / C, c = d % C;
    const ushort_t* src = A + (size_t)(mb + r) * KD + ((c ^ (r & 7)) << 3);
    gl_lds16(src, Aw + i * 512);
  }
  asm volatile("s_waitcnt vmcnt(0)" ::: "memory");
  __builtin_amdgcn_sched_barrier(0);

  f32x4 acc[16];
  #pragma unroll
  for (int j = 0; j < 16; j++) acc[j] = (f32x4){0.f, 0.f, 0.f, 0.f};

  const ushort_t* bp = Wb + (size_t)(n0 + fr) * KD + fg * 8;
  #pragma unroll
  for (int kt = 0; kt < KD / 32; kt++) {
    bf16x8 a = *reinterpret_cast<const bf16x8*>(
        &Aw[(fr * C + ((kt * 4 + fg) ^ (fr & 7))) << 3]);
    #pragma unroll
    for (int j = 0; j < 16; j++) {
      bf16x8 bf = *reinterpret_cast<const bf16x8*>(bp + (size_t)j * 16 * KD + kt * 32);
      acc[j] = MFMA(a, bf, acc[j], 0, 0, 0);
    }
  }

  int mrow0 = mb + fg * 4;
  #pragma unroll
  for (int j = 0; j < 16; j++) {
    int n = n0 + j * 16 + fr;
    float bs = bias[n];
    #pragma unroll
    for (int r = 0; r < 4; r++) {
      int m = mrow0 + r;
      float v = acc[j][r] + bs;
      if (RES) v += res[(size_t)m * Ndim + n];
      if (GELU) v = 0.5f * v * (1.f + erff(v * 0.70710678118f));
      if (OUTBF16) ((ushort_t*)outp)[(size_t)m * Ndim + n] = f2bfbits(v);
      else         ((float*)outp)[(size_t)m * Ndim + n] = v;
    }
  }
}

// -------- MFMA flash attention v6: 32KB LDS, exp2 softmax, defer-rescale --------
__global__ __launch_bounds__(512) void k_mattn6(const ushort_t* __restrict__ QKV,
                                                const int* __restrict__ lens,
                                                ushort_t* __restrict__ O) {
  int b = blockIdx.z, h = blockIdx.y;
  int len = lens[b];
  int q0 = blockIdx.x * 128;
  if (q0 >= len) return;
  int t = threadIdx.x, lane = t & 63, w = t >> 6;
  int fr = lane & 15, fg = lane >> 4;
  __shared__ __align__(16) ushort_t Kh[8192];   // [128 k][64 d], chunk ^= (k&7)
  __shared__ __align__(16) ushort_t Vh[8192];   // [64 d][128 k], chunk ^= S(d)&7

  const ushort_t* base = QKV + (size_t)b * LL * 768;
  int qw = q0 + w * 16;
  bool qact = qw < len;
  int q = qw + fr;

  const ushort_t* qp = base + (size_t)q * 768 + h * 64 + fg * 8;
  bf16x8 qf0 = *reinterpret_cast<const bf16x8*>(qp);
  bf16x8 qf1 = *reinterpret_cast<const bf16x8*>(qp + 32);

  const float SC = 0.125f * 1.44269504f;
  f32x4 ot[4];
  #pragma unroll
  for (int df = 0; df < 4; df++) ot[df] = (f32x4){0.f, 0.f, 0.f, 0.f};
  float m_run = -1e30f, lsum = 0.f;

  for (int kb = 0; kb < len; kb += 128) {
    if (kb) __syncthreads();
    int lim = min(128, len - kb);
    #pragma unroll
    for (int rr = 0; rr < 2; rr++) {
      if (rr * 64 >= lim) break;
      int krow = rr * 64 + w * 8 + (lane >> 3);
      int gk = kb + krow; if (gk > len - 1) gk = len - 1;
      int ch = lane & 7;
      const ushort_t* src = base + (size_t)gk * 768 + 256 + h * 64 + ((ch ^ (krow & 7)) << 3);
      gl_lds16(src, &Kh[rr * 4096 + w * 512]);
    }
    #pragma unroll
    for (int it = 0; it < 2; it++) {
      if (it * 64 >= lim) break;
      int c = it * 512 + t;
      int k = c >> 3, dg = c & 7;
      int gk = kb + k; if (gk > len - 1) gk = len - 1;
      uint4 vv = *reinterpret_cast<const uint4*>(base + (size_t)gk * 768 + 512 + h * 64 + dg * 8);
      unsigned uu[4] = {vv.x, vv.y, vv.z, vv.w};
      #pragma unroll
      for (int j = 0; j < 4; j++) {
        int d0 = dg * 8 + j * 2, d1 = d0 + 1;
        int s0 = (d0 ^ (d0 >> 3)) & 7, s1 = (d1 ^ (d1 >> 3)) & 7;
        Vh[d0 * 128 + (((k >> 3) ^ s0) << 3) + (k & 7)] = (ushort_t)(uu[j] & 0xffff);
        Vh[d1 * 128 + (((k >> 3) ^ s1) << 3) + (k & 7)] = (ushort_t)(uu[j] >> 16);
      }
    }
    __syncthreads();

    if (qact) {
      for (int kt = 0; kt < lim; kt += 64) {
        f32x4 s[4];
        #pragma unroll
        for (int f = 0; f < 4; f++) {
          s[f] = (f32x4){0.f, 0.f, 0.f, 0.f};
          int krow = kt + f * 16 + fr;
          const ushort_t* kp0 = &Kh[krow * 64 + ((fg ^ (krow & 7)) << 3)];
          const ushort_t* kp1 = &Kh[krow * 64 + (((4 + fg) ^ (krow & 7)) << 3)];
          s[f] = MFMA(*reinterpret_cast<const bf16x8*>(kp0), qf0, s[f], 0, 0, 0);
          s[f] = MFMA(*reinterpret_cast<const bf16x8*>(kp1), qf1, s[f], 0, 0, 0);
        }
        int rem = lim - kt;
        #pragma unroll
        for (int f = 0; f < 4; f++)
          #pragma unroll
          for (int r = 0; r < 4; r++)
            s[f][r] = (f * 16 + fg * 4 + r < rem) ? s[f][r] * SC : -1e30f;
        float tm = -1e30f;
        #pragma unroll
        for (int f = 0; f < 4; f++)
          #pragma unroll
          for (int r = 0; r < 4; r++) tm = fmaxf(tm, s[f][r]);
        tm = fmaxf(tm, __shfl_xor(tm, 16, 64));
        tm = fmaxf(tm, __shfl_xor(tm, 32, 64));
        bool grow = tm > m_run;
        if (__any(grow)) {
          float m_new = grow ? tm : m_run;
          float corr = exp2f(m_run - m_new);
          lsum *= corr;
          #pragma unroll
          for (int df = 0; df < 4; df++)
            #pragma unroll
            for (int r = 0; r < 4; r++) ot[df][r] *= corr;
          m_run = m_new;
        }
        float ps = 0.f;
        #pragma unroll
        for (int f = 0; f < 4; f++)
          #pragma unroll
          for (int r = 0; r < 4; r++) {
            float p = exp2f(s[f][r] - m_run);
            s[f][r] = p; ps += p;
          }
        ps += __shfl_xor(ps, 16, 64);
        ps += __shfl_xor(ps, 32, 64);
        lsum += ps;
        #pragma unroll
        for (int st = 0; st < 2; st++) {
          int fA = st * 2, fB = fA + 1;
          unsigned a0 = pkbf(s[fA][0], s[fA][1]), a1 = pkbf(s[fA][2], s[fA][3]);
          unsigned b0 = pkbf(s[fB][0], s[fB][1]), b1 = pkbf(s[fB][2], s[fB][3]);
          int sA = ((fg & 1) * 2) * 16 + fr;
          int sB = sA + 16;
          unsigned wa0 = __shfl(a0, sA, 64), wb0 = __shfl(b0, sA, 64);
          unsigned wa1 = __shfl(a1, sA, 64), wb1 = __shfl(b1, sA, 64);
          unsigned wa2 = __shfl(a0, sB, 64), wb2 = __shfl(b0, sB, 64);
          unsigned wa3 = __shfl(a1, sB, 64), wb3 = __shfl(b1, sB, 64);
          bool lo = fg < 2;
          U8 pf;
          pf.u[0] = lo ? wa0 : wb0; pf.u[1] = lo ? wa1 : wb1;
          pf.u[2] = lo ? wa2 : wb2; pf.u[3] = lo ? wa3 : wb3;
          int cb = (kt >> 3) + st * 4 + fg;
          #pragma unroll
          for (int df = 0; df < 4; df++) {
            int d = df * 16 + fr;
            int sd = (d ^ (d >> 3)) & 7;
            const ushort_t* vp = &Vh[d * 128 + ((cb ^ sd) << 3)];
            ot[df] = MFMA(*reinterpret_cast<const bf16x8*>(vp), pf.v, ot[df], 0, 0, 0);
          }
        }
      }
    }
  }

  if (q < len) {
    float linv = 1.f / lsum;
    #pragma unroll
    for (int df = 0; df < 4; df++) {
      ushort4 ov;
      ov.x = f2bfbits(ot[df][0] * linv);
      ov.y = f2bfbits(ot[df][1] * linv);
      ov.z = f2bfbits(ot[df][2] * linv);
      ov.w = f2bfbits(ot[df][3] * linv);
      *reinterpret_cast<ushort4*>(O + (size_t)(b * LL + q) * DD + h * 64 + df * 16 + fg * 4) = ov;
    }
  }
}

// -------- final attention pooling --------
__global__ __launch_bounds__(256) void k_pool(const float* __restrict__ X,
                                              const int* __restrict__ lens,
                                              bf16* __restrict__ pooled) {
  __shared__ float red[4];
  __shared__ float qs[DD];
  __shared__ float sc[LL];
  int b = blockIdx.x, t = threadIdx.x;
  int len = lens[b];
  const float* Xb = X + (size_t)b * LL * DD;
  qs[t] = Xb[(size_t)(len - 1) * DD + t];
  __syncthreads();
  for (int l = t; l < LL; l += 256) {
    float s = -1e30f;
    if (l < len) {
      const float4* xr = reinterpret_cast<const float4*>(Xb + (size_t)l * DD);
      const float4* qq = reinterpret_cast<const float4*>(qs);
      float a0 = 0, a1 = 0, a2 = 0, a3 = 0;
      for (int k4 = 0; k4 < 64; k4++) {
        float4 xv = xr[k4], qv = qq[k4];
        a0 += xv.x * qv.x; a1 += xv.y * qv.y; a2 += xv.z * qv.z; a3 += xv.w * qv.w;
      }
      s = (a0 + a1) + (a2 + a3);
    }
    sc[l] = s;
  }
  __syncthreads();
  float mx = fmaxf(sc[t], sc[t + 256]);
  #pragma unroll
  for (int off = 32; off > 0; off >>= 1) mx = fmaxf(mx, __shfl_down(mx, off, 64));
  __syncthreads();
  if ((t & 63) == 0) red[t >> 6] = mx;
  __syncthreads();
  mx = fmaxf(fmaxf(red[0], red[1]), fmaxf(red[2], red[3]));
  float e0 = (t < len) ? __expf(sc[t] - mx) : 0.f;
  float e1 = (t + 256 < len) ? __expf(sc[t + 256] - mx) : 0.f;
  float ssum = blk_sum(e0 + e1, red);
  float inv = 1.f / ssum;
  __syncthreads();
  sc[t] = e0 * inv; sc[t + 256] = e1 * inv;
  __syncthreads();
  float acc = 0.f;
  for (int l = 0; l < len; l++) acc += sc[l] * Xb[(size_t)l * DD + t];
  pooled[b * DD + t] = __float2bfloat16(acc);
}

// -------- classifier --------
__global__ __launch_bounds__(512) void k_cls(const ushort_t* __restrict__ POOL,
                                             const float* __restrict__ W,
                                             const float* __restrict__ bias,
                                             float* __restrict__ out) {
  int t = threadIdx.x, lane = t & 63, w = t >> 6;
  int fr = lane & 15, fg = lane >> 4;
  int n = blockIdx.x * 128 + w * 16 + fr;
  const float* wp = W + (size_t)n * DD + fg * 8;
  f32x4 acc[4];
  #pragma unroll
  for (int i = 0; i < 4; i++) acc[i] = (f32x4){0.f, 0.f, 0.f, 0.f};
  for (int k0 = 0; k0 < DD; k0 += 32) {
    float4 f0 = *reinterpret_cast<const float4*>(wp + k0);
    float4 f1 = *reinterpret_cast<const float4*>(wp + k0 + 4);
    U8 bfr;
    bfr.u[0] = pkbf(f0.x, f0.y); bfr.u[1] = pkbf(f0.z, f0.w);
    bfr.u[2] = pkbf(f1.x, f1.y); bfr.u[3] = pkbf(f1.z, f1.w);
    #pragma unroll
    for (int i = 0; i < 4; i++) {
      bf16x8 af = *reinterpret_cast<const bf16x8*>(POOL + (size_t)(i * 16 + fr) * DD + k0 + fg * 8);
      acc[i] = MFMA(af, bfr.v, acc[i], 0, 0, 0);
    }
  }
  float bs = bias[n];
  #pragma unroll
  for (int i = 0; i < 4; i++)
    #pragma unroll
    for (int r = 0; r < 4; r++)
      out[(size_t)(i * 16 + fg * 4 + r) * VV + n] = acc[i][r] + bs;
}

extern "C" void kernel_launch(void* const* d_in, const int* in_sizes, int n_in,
                              void* d_out, int out_size, void* d_ws, size_t ws_size,
                              hipStream_t stream) {
  const int*   tokens  = (const int*)d_in[0];
  const float* tok_emb = (const float*)d_in[2];
  const float* pos_emb = (const float*)d_in[3];
  const float* emb_g   = (const float*)d_in[4];
  const float* emb_b   = (const float*)d_in[5];
  const float* ln1_g   = (const float*)d_in[6];
  const float* ln1_b   = (const float*)d_in[7];
  const float* Wqkv    = (const float*)d_in[8];
  const float* bqkv    = (const float*)d_in[9];
  const float* Wo      = (const float*)d_in[10];
  const float* bo      = (const float*)d_in[11];
  const float* ln2_g   = (const float*)d_in[12];
  const float* ln2_b   = (const float*)d_in[13];
  const float* W1      = (const float*)d_in[14];
  const float* b1      = (const float*)d_in[15];
  const float* W2      = (const float*)d_in[16];
  const float* b2      = (const float*)d_in[17];
  const float* cls_W   = (const float*)d_in[22];
  const float* cls_b   = (const float*)d_in[23];

  char* ws = (char*)d_ws;
  float*    X    = (float*)ws;                         // 33,554,432 B
  ushort_t* QKV  = (ushort_t*)(ws + 33554432);         // 50,331,648 B (QKV [m][768] / FF1 [m][512])
  ushort_t* Hb   = (ushort_t*)(ws + 83886080);         // 16,777,216 B
  ushort_t* WB   = (ushort_t*)(ws + 100663296);        //  1,048,576 B per-layer weights bf16
  ushort_t* POOL = (ushort_t*)(ws + 101711872);        //     32,768 B
  int*      LEN  = (int*)(ws + 101744640);             //        256 B

  const int OFF_QKV = 0, OFF_WO = 196608, OFF_W1 = 262144, OFF_W2 = 393216;

  k_lens<<<BB, 256, 0, stream>>>(tokens, LEN);
  k_embed4<<<MM / 4, 256, 0, stream>>>(tokens, tok_emb, pos_emb, emb_g, emb_b, X);

  for (int e = 0; e < KK; e++) {
    k_cvtw<<<512, 256, 0, stream>>>(Wqkv + (size_t)e * 196608, Wo + (size_t)e * 65536,
                                    W1 + (size_t)e * 131072, W2 + (size_t)e * 131072, WB);
    k_ln4<<<MM / 4, 256, 0, stream>>>(X, ln1_g + e * DD, ln1_b + e * DD, LEN, (bf16*)Hb);
    k_wgemm<256, false, false, true><<<dim3(3, 512), 256, 0, stream>>>(
        Hb, WB + OFF_QKV, bqkv + e * 3 * DD, nullptr, QKV, LEN, 3 * DD);
    k_mattn6<<<dim3(4, HH, BB), 512, 0, stream>>>(QKV, LEN, Hb);
    k_wgemm<256, false, true, false><<<dim3(1, 512), 256, 0, stream>>>(
        Hb, WB + OFF_WO, bo + e * DD, X, X, LEN, DD);
    k_ln4<<<MM / 4, 256, 0, stream>>>(X, ln2_g + e * DD, ln2_b + e * DD, LEN, (bf16*)Hb);
    k_wgemm<256, true, false, true><<<dim3(2, 512), 256, 0, stream>>>(
        Hb, WB + OFF_W1, b1 + e * FF, nullptr, QKV, LEN, FF);
    k_wgemm<512, false, true, false><<<dim3(1, 512), 256, 0, stream>>>(
        QKV, WB + OFF_W2, b2 + e * DD, X, X, LEN, DD);
  }

  k_pool<<<BB, 256, 0, stream>>>(X, LEN, (bf16*)POOL);
  k_cls<<<dim3(VV / 128), 512, 0, stream>>>(POOL, cls_W, cls_b, (float*)d_out);
}

// Round 10
// 879.494 us; speedup vs baseline: 2.6484x; 2.6484x over previous
//
#include <hip/hip_runtime.h>
#include <hip/hip_bf16.h>

#define BB 64
#define LL 512
#define DD 256
#define VV 32000
#define KK 6
#define HH 4
#define FF 512
#define MM (BB * LL)

typedef __hip_bfloat16 bf16;
typedef unsigned short ushort_t;
typedef __attribute__((ext_vector_type(8))) __bf16 bf16x8;
typedef __attribute__((ext_vector_type(4))) float f32x4;
#define MFMA __builtin_amdgcn_mfma_f32_16x16x32_bf16

__device__ __forceinline__ ushort_t f2bfbits(float x) {
  return __builtin_bit_cast(unsigned short, (__bf16)x);
}
__device__ __forceinline__ unsigned pkbf(float lo, float hi) {
  return (unsigned)f2bfbits(lo) | ((unsigned)f2bfbits(hi) << 16);
}
union U8 { unsigned u[4]; bf16x8 v; };

// async global->LDS, 16B/lane; dest must be WAVE-UNIFORM base (HW adds lane*16)
__device__ __forceinline__ void gl_lds16(const ushort_t* g, ushort_t* l) {
  __builtin_amdgcn_global_load_lds(
      (const __attribute__((address_space(1))) unsigned int*)g,
      (__attribute__((address_space(3))) unsigned int*)l, 16, 0, 0);
}

__device__ __forceinline__ float blk_sum(float v, float* red) {
  #pragma unroll
  for (int o = 32; o > 0; o >>= 1) v += __shfl_down(v, o, 64);
  __syncthreads();
  if ((threadIdx.x & 63) == 0) red[threadIdx.x >> 6] = v;
  __syncthreads();
  return red[0] + red[1] + red[2] + red[3];
}

__global__ __launch_bounds__(256) void k_lens(const int* __restrict__ tokens, int* __restrict__ lens) {
  __shared__ float red[4];
  int b = blockIdx.x, t = threadIdx.x;
  float c = (tokens[b * LL + t] != 0 ? 1.f : 0.f) + (tokens[b * LL + 256 + t] != 0 ? 1.f : 0.f);
  float s = blk_sum(c, red);
  if (t == 0) lens[b] = (int)(s + 0.5f);
}

__global__ __launch_bounds__(256) void k_embed4(const int* __restrict__ tokens,
                                                const float* __restrict__ tok_emb,
                                                const float* __restrict__ pos_emb,
                                                const float* __restrict__ g,
                                                const float* __restrict__ be,
                                                float* __restrict__ X) {
  int wid = threadIdx.x >> 6, lane = threadIdx.x & 63;
  int row = blockIdx.x * 4 + wid;
  int l = row & (LL - 1);
  int tok = tokens[row];
  float4 a = *reinterpret_cast<const float4*>(tok_emb + (size_t)tok * DD + lane * 4);
  float4 p = *reinterpret_cast<const float4*>(pos_emb + (size_t)l * DD + lane * 4);
  float4 v = {a.x + p.x, a.y + p.y, a.z + p.z, a.w + p.w};
  float s = v.x + v.y + v.z + v.w;
  float q = v.x * v.x + v.y * v.y + v.z * v.z + v.w * v.w;
  #pragma unroll
  for (int o = 32; o > 0; o >>= 1) { s += __shfl_xor(s, o, 64); q += __shfl_xor(q, o, 64); }
  float mu = s * (1.f / DD);
  float rstd = rsqrtf(q * (1.f / DD) - mu * mu + 1e-5f);
  float4 gv = *reinterpret_cast<const float4*>(g + lane * 4);
  float4 bv = *reinterpret_cast<const float4*>(be + lane * 4);
  float4 o4 = {(v.x - mu) * rstd * gv.x + bv.x, (v.y - mu) * rstd * gv.y + bv.y,
               (v.z - mu) * rstd * gv.z + bv.z, (v.w - mu) * rstd * gv.w + bv.w};
  *reinterpret_cast<float4*>(X + (size_t)row * DD + lane * 4) = o4;
}

__global__ __launch_bounds__(256) void k_ln4(const float* __restrict__ X,
                                             const float* __restrict__ g,
                                             const float* __restrict__ be,
                                             const int* __restrict__ lens,
                                             bf16* __restrict__ H) {
  int wid = threadIdx.x >> 6, lane = threadIdx.x & 63;
  int row = blockIdx.x * 4 + wid;
  int b = row >> 9, l = row & (LL - 1);
  if (l >= lens[b]) return;
  float4 v = *reinterpret_cast<const float4*>(X + (size_t)row * DD + lane * 4);
  float s = v.x + v.y + v.z + v.w;
  float q = v.x * v.x + v.y * v.y + v.z * v.z + v.w * v.w;
  #pragma unroll
  for (int o = 32; o > 0; o >>= 1) { s += __shfl_xor(s, o, 64); q += __shfl_xor(q, o, 64); }
  float mu = s * (1.f / DD);
  float rstd = rsqrtf(q * (1.f / DD) - mu * mu + 1e-5f);
  float4 gv = *reinterpret_cast<const float4*>(g + lane * 4);
  float4 bv = *reinterpret_cast<const float4*>(be + lane * 4);
  ushort4 o4;
  o4.x = f2bfbits((v.x - mu) * rstd * gv.x + bv.x);
  o4.y = f2bfbits((v.y - mu) * rstd * gv.y + bv.y);
  o4.z = f2bfbits((v.z - mu) * rstd * gv.z + bv.z);
  o4.w = f2bfbits((v.w - mu) * rstd * gv.w + bv.w);
  *reinterpret_cast<ushort4*>((ushort_t*)H + (size_t)row * DD + lane * 4) = o4;
}

__global__ __launch_bounds__(256) void k_cvtw(const float* __restrict__ w0, const float* __restrict__ w1,
                                              const float* __restrict__ w2, const float* __restrict__ w3,
                                              ushort_t* __restrict__ d) {
  int i = (blockIdx.x * 256 + threadIdx.x) * 4;
  const float* s; int off;
  if (i < 196608)      { s = w0; off = i; }
  else if (i < 262144) { s = w1; off = i - 196608; }
  else if (i < 393216) { s = w2; off = i - 262144; }
  else                 { s = w3; off = i - 393216; }
  float4 v = *reinterpret_cast<const float4*>(s + off);
  ushort4 o;
  o.x = f2bfbits(v.x); o.y = f2bfbits(v.y); o.z = f2bfbits(v.z); o.w = f2bfbits(v.w);
  *reinterpret_cast<ushort4*>(d + i) = o;
}

// -------- MFMA GEMM: MT x NT tile, BK=32, 4 waves, TRIPLE-buffer + counted vmcnt --------
// Sync structure (T3/T4): STAGE(next) -> s_waitcnt vmcnt(L) -> raw s_barrier ->
// ds_read+MFMA. Prefetch loads stay in flight across the barrier (never drained
// to 0 in-loop). 3 buffers make the single barrier race-free: writes at iter k
// go to buf (k+1)%3; concurrent reads touch only buf k%3 / (k+2)%3.
// LDS: L[row][c] = G[row][c ^ ((row>>1)&3)] (16B chunks) -> conflict-free b128.
template <int MT, int NT, int KD, bool GELU, bool RES, bool OUTBF16>
__global__ __launch_bounds__(256) void k_mgemm(const ushort_t* __restrict__ A,
                                               const ushort_t* __restrict__ Wb,
                                               const float* __restrict__ bias,
                                               const float* __restrict__ res,
                                               void* __restrict__ outp,
                                               const int* __restrict__ lens,
                                               int Ndim) {
  constexpr int JF = (MT == 128) ? (NT / 32) : (NT / 64);  // n-frags per wave
  constexpr int AR = MT / 64, BR = NT / 64;                // staging rounds
  constexpr int L = AR + BR;                               // gl_lds per wave per stage
  constexpr int NK = KD / 32;
  int n0 = blockIdx.x * NT, m0 = blockIdx.y * MT;
  if ((m0 & (LL - 1)) >= lens[m0 >> 9]) return;            // whole tile is padding
  __shared__ __align__(16) ushort_t As[3][MT * 32];
  __shared__ __align__(16) ushort_t Bs[3][NT * 32];
  int t = threadIdx.x, lane = t & 63, w = t >> 6;
  int wr = (MT == 128) ? (w >> 1) * 64 : 0;
  int wc = (MT == 128) ? (w & 1) * (NT / 2) : w * (NT / 4);
  int fr = lane & 15, fg = lane >> 4;

  int ca = lane & 3;
  const ushort_t* gA[AR];
  #pragma unroll
  for (int ra = 0; ra < AR; ra++) {
    int row = ra * 64 + (t >> 2);
    gA[ra] = A + (size_t)(m0 + row) * KD + ((ca ^ ((row >> 1) & 3)) << 3);
  }
  const ushort_t* gB[BR];
  #pragma unroll
  for (int rb = 0; rb < BR; rb++) {
    int row = rb * 64 + (t >> 2);
    gB[rb] = Wb + (size_t)(n0 + row) * KD + ((ca ^ ((row >> 1) & 3)) << 3);
  }

  f32x4 acc[4][JF];
  #pragma unroll
  for (int i = 0; i < 4; i++)
    #pragma unroll
    for (int j = 0; j < JF; j++) acc[i][j] = (f32x4){0.f, 0.f, 0.f, 0.f};

  #define STAGE(bi, koff) { \
    _Pragma("unroll") for (int ra = 0; ra < AR; ra++) gl_lds16(gA[ra] + (koff), &As[bi][ra * 2048 + w * 512]); \
    _Pragma("unroll") for (int rb = 0; rb < BR; rb++) gl_lds16(gB[rb] + (koff), &Bs[bi][rb * 2048 + w * 512]); }

  STAGE(0, 0);
  #pragma unroll
  for (int kt = 0; kt < NK; kt++) {
    int cur = kt % 3;
    if (kt + 1 < NK) {
      STAGE((kt + 1) % 3, (kt + 1) * 32);
      asm volatile("s_waitcnt vmcnt(%0)" :: "n"(L) : "memory");
    } else {
      asm volatile("s_waitcnt vmcnt(0)" ::: "memory");
    }
    __builtin_amdgcn_s_barrier();
    __builtin_amdgcn_sched_barrier(0);
    bf16x8 af[4], bfr[JF];
    #pragma unroll
    for (int i = 0; i < 4; i++) {
      int row = wr + i * 16 + fr;
      af[i] = *reinterpret_cast<const bf16x8*>(&As[cur][row * 32 + ((fg ^ ((row >> 1) & 3)) << 3)]);
    }
    #pragma unroll
    for (int j = 0; j < JF; j++) {
      int row = wc + j * 16 + fr;
      bfr[j] = *reinterpret_cast<const bf16x8*>(&Bs[cur][row * 32 + ((fg ^ ((row >> 1) & 3)) << 3)]);
    }
    #pragma unroll
    for (int i = 0; i < 4; i++)
      #pragma unroll
      for (int j = 0; j < JF; j++)
        acc[i][j] = MFMA(af[i], bfr[j], acc[i][j], 0, 0, 0);
  }
  #undef STAGE

  #pragma unroll
  for (int i = 0; i < 4; i++) {
    int mbase = m0 + wr + i * 16 + fg * 4;
    #pragma unroll
    for (int j = 0; j < JF; j++) {
      int n = n0 + wc + j * 16 + fr;
      float bs = bias[n];
      #pragma unroll
      for (int r = 0; r < 4; r++) {
        int m = mbase + r;
        float v = acc[i][j][r] + bs;
        if (RES) v += res[(size_t)m * Ndim + n];
        if (GELU) v = 0.5f * v * (1.f + erff(v * 0.70710678118f));
        if (OUTBF16) ((ushort_t*)outp)[(size_t)m * Ndim + n] = f2bfbits(v);
        else         ((float*)outp)[(size_t)m * Ndim + n] = v;
      }
    }
  }
}

// -------- MFMA flash attention v6: 32KB LDS, exp2 softmax, defer-rescale --------
__global__ __launch_bounds__(512) void k_mattn6(const ushort_t* __restrict__ QKV,
                                                const int* __restrict__ lens,
                                                ushort_t* __restrict__ O) {
  int b = blockIdx.z, h = blockIdx.y;
  int len = lens[b];
  int q0 = blockIdx.x * 128;
  if (q0 >= len) return;
  int t = threadIdx.x, lane = t & 63, w = t >> 6;
  int fr = lane & 15, fg = lane >> 4;
  __shared__ __align__(16) ushort_t Kh[8192];   // [128 k][64 d], chunk ^= (k&7)
  __shared__ __align__(16) ushort_t Vh[8192];   // [64 d][128 k], chunk ^= S(d)&7

  const ushort_t* base = QKV + (size_t)b * LL * 768;
  int qw = q0 + w * 16;
  bool qact = qw < len;
  int q = qw + fr;

  const ushort_t* qp = base + (size_t)q * 768 + h * 64 + fg * 8;
  bf16x8 qf0 = *reinterpret_cast<const bf16x8*>(qp);
  bf16x8 qf1 = *reinterpret_cast<const bf16x8*>(qp + 32);

  const float SC = 0.125f * 1.44269504f;
  f32x4 ot[4];
  #pragma unroll
  for (int df = 0; df < 4; df++) ot[df] = (f32x4){0.f, 0.f, 0.f, 0.f};
  float m_run = -1e30f, lsum = 0.f;

  for (int kb = 0; kb < len; kb += 128) {
    if (kb) __syncthreads();
    int lim = min(128, len - kb);
    #pragma unroll
    for (int rr = 0; rr < 2; rr++) {
      if (rr * 64 >= lim) break;
      int krow = rr * 64 + w * 8 + (lane >> 3);
      int gk = kb + krow; if (gk > len - 1) gk = len - 1;
      int ch = lane & 7;
      const ushort_t* src = base + (size_t)gk * 768 + 256 + h * 64 + ((ch ^ (krow & 7)) << 3);
      gl_lds16(src, &Kh[rr * 4096 + w * 512]);
    }
    #pragma unroll
    for (int it = 0; it < 2; it++) {
      if (it * 64 >= lim) break;
      int c = it * 512 + t;
      int k = c >> 3, dg = c & 7;
      int gk = kb + k; if (gk > len - 1) gk = len - 1;
      uint4 vv = *reinterpret_cast<const uint4*>(base + (size_t)gk * 768 + 512 + h * 64 + dg * 8);
      unsigned uu[4] = {vv.x, vv.y, vv.z, vv.w};
      #pragma unroll
      for (int j = 0; j < 4; j++) {
        int d0 = dg * 8 + j * 2, d1 = d0 + 1;
        int s0 = (d0 ^ (d0 >> 3)) & 7, s1 = (d1 ^ (d1 >> 3)) & 7;
        Vh[d0 * 128 + (((k >> 3) ^ s0) << 3) + (k & 7)] = (ushort_t)(uu[j] & 0xffff);
        Vh[d1 * 128 + (((k >> 3) ^ s1) << 3) + (k & 7)] = (ushort_t)(uu[j] >> 16);
      }
    }
    __syncthreads();

    if (qact) {
      for (int kt = 0; kt < lim; kt += 64) {
        f32x4 s[4];
        #pragma unroll
        for (int f = 0; f < 4; f++) {
          s[f] = (f32x4){0.f, 0.f, 0.f, 0.f};
          int krow = kt + f * 16 + fr;
          const ushort_t* kp0 = &Kh[krow * 64 + ((fg ^ (krow & 7)) << 3)];
          const ushort_t* kp1 = &Kh[krow * 64 + (((4 + fg) ^ (krow & 7)) << 3)];
          s[f] = MFMA(*reinterpret_cast<const bf16x8*>(kp0), qf0, s[f], 0, 0, 0);
          s[f] = MFMA(*reinterpret_cast<const bf16x8*>(kp1), qf1, s[f], 0, 0, 0);
        }
        int rem = lim - kt;
        #pragma unroll
        for (int f = 0; f < 4; f++)
          #pragma unroll
          for (int r = 0; r < 4; r++)
            s[f][r] = (f * 16 + fg * 4 + r < rem) ? s[f][r] * SC : -1e30f;
        float tm = -1e30f;
        #pragma unroll
        for (int f = 0; f < 4; f++)
          #pragma unroll
          for (int r = 0; r < 4; r++) tm = fmaxf(tm, s[f][r]);
        tm = fmaxf(tm, __shfl_xor(tm, 16, 64));
        tm = fmaxf(tm, __shfl_xor(tm, 32, 64));
        bool grow = tm > m_run;
        if (__any(grow)) {
          float m_new = grow ? tm : m_run;
          float corr = exp2f(m_run - m_new);
          lsum *= corr;
          #pragma unroll
          for (int df = 0; df < 4; df++)
            #pragma unroll
            for (int r = 0; r < 4; r++) ot[df][r] *= corr;
          m_run = m_new;
        }
        float ps = 0.f;
        #pragma unroll
        for (int f = 0; f < 4; f++)
          #pragma unroll
          for (int r = 0; r < 4; r++) {
            float p = exp2f(s[f][r] - m_run);
            s[f][r] = p; ps += p;
          }
        ps += __shfl_xor(ps, 16, 64);
        ps += __shfl_xor(ps, 32, 64);
        lsum += ps;
        #pragma unroll
        for (int st = 0; st < 2; st++) {
          int fA = st * 2, fB = fA + 1;
          unsigned a0 = pkbf(s[fA][0], s[fA][1]), a1 = pkbf(s[fA][2], s[fA][3]);
          unsigned b0 = pkbf(s[fB][0], s[fB][1]), b1 = pkbf(s[fB][2], s[fB][3]);
          int sA = ((fg & 1) * 2) * 16 + fr;
          int sB = sA + 16;
          unsigned wa0 = __shfl(a0, sA, 64), wb0 = __shfl(b0, sA, 64);
          unsigned wa1 = __shfl(a1, sA, 64), wb1 = __shfl(b1, sA, 64);
          unsigned wa2 = __shfl(a0, sB, 64), wb2 = __shfl(b0, sB, 64);
          unsigned wa3 = __shfl(a1, sB, 64), wb3 = __shfl(b1, sB, 64);
          bool lo = fg < 2;
          U8 pf;
          pf.u[0] = lo ? wa0 : wb0; pf.u[1] = lo ? wa1 : wb1;
          pf.u[2] = lo ? wa2 : wb2; pf.u[3] = lo ? wa3 : wb3;
          int cb = (kt >> 3) + st * 4 + fg;
          #pragma unroll
          for (int df = 0; df < 4; df++) {
            int d = df * 16 + fr;
            int sd = (d ^ (d >> 3)) & 7;
            const ushort_t* vp = &Vh[d * 128 + ((cb ^ sd) << 3)];
            ot[df] = MFMA(*reinterpret_cast<const bf16x8*>(vp), pf.v, ot[df], 0, 0, 0);
          }
        }
      }
    }
  }

  if (q < len) {
    float linv = 1.f / lsum;
    #pragma unroll
    for (int df = 0; df < 4; df++) {
      ushort4 ov;
      ov.x = f2bfbits(ot[df][0] * linv);
      ov.y = f2bfbits(ot[df][1] * linv);
      ov.z = f2bfbits(ot[df][2] * linv);
      ov.w = f2bfbits(ot[df][3] * linv);
      *reinterpret_cast<ushort4*>(O + (size_t)(b * LL + q) * DD + h * 64 + df * 16 + fg * 4) = ov;
    }
  }
}

// -------- final attention pooling --------
__global__ __launch_bounds__(256) void k_pool(const float* __restrict__ X,
                                              const int* __restrict__ lens,
                                              bf16* __restrict__ pooled) {
  __shared__ float red[4];
  __shared__ float qs[DD];
  __shared__ float sc[LL];
  int b = blockIdx.x, t = threadIdx.x;
  int len = lens[b];
  const float* Xb = X + (size_t)b * LL * DD;
  qs[t] = Xb[(size_t)(len - 1) * DD + t];
  __syncthreads();
  for (int l = t; l < LL; l += 256) {
    float s = -1e30f;
    if (l < len) {
      const float4* xr = reinterpret_cast<const float4*>(Xb + (size_t)l * DD);
      const float4* qq = reinterpret_cast<const float4*>(qs);
      float a0 = 0, a1 = 0, a2 = 0, a3 = 0;
      for (int k4 = 0; k4 < 64; k4++) {
        float4 xv = xr[k4], qv = qq[k4];
        a0 += xv.x * qv.x; a1 += xv.y * qv.y; a2 += xv.z * qv.z; a3 += xv.w * qv.w;
      }
      s = (a0 + a1) + (a2 + a3);
    }
    sc[l] = s;
  }
  __syncthreads();
  float mx = fmaxf(sc[t], sc[t + 256]);
  #pragma unroll
  for (int off = 32; off > 0; off >>= 1) mx = fmaxf(mx, __shfl_down(mx, off, 64));
  __syncthreads();
  if ((t & 63) == 0) red[t >> 6] = mx;
  __syncthreads();
  mx = fmaxf(fmaxf(red[0], red[1]), fmaxf(red[2], red[3]));
  float e0 = (t < len) ? __expf(sc[t] - mx) : 0.f;
  float e1 = (t + 256 < len) ? __expf(sc[t + 256] - mx) : 0.f;
  float ssum = blk_sum(e0 + e1, red);
  float inv = 1.f / ssum;
  __syncthreads();
  sc[t] = e0 * inv; sc[t + 256] = e1 * inv;
  __syncthreads();
  float acc = 0.f;
  for (int l = 0; l < len; l++) acc += sc[l] * Xb[(size_t)l * DD + t];
  pooled[b * DD + t] = __float2bfloat16(acc);
}

// -------- classifier --------
__global__ __launch_bounds__(512) void k_cls(const ushort_t* __restrict__ POOL,
                                             const float* __restrict__ W,
                                             const float* __restrict__ bias,
                                             float* __restrict__ out) {
  int t = threadIdx.x, lane = t & 63, w = t >> 6;
  int fr = lane & 15, fg = lane >> 4;
  int n = blockIdx.x * 128 + w * 16 + fr;
  const float* wp = W + (size_t)n * DD + fg * 8;
  f32x4 acc[4];
  #pragma unroll
  for (int i = 0; i < 4; i++) acc[i] = (f32x4){0.f, 0.f, 0.f, 0.f};
  for (int k0 = 0; k0 < DD; k0 += 32) {
    float4 f0 = *reinterpret_cast<const float4*>(wp + k0);
    float4 f1 = *reinterpret_cast<const float4*>(wp + k0 + 4);
    U8 bfr;
    bfr.u[0] = pkbf(f0.x, f0.y); bfr.u[1] = pkbf(f0.z, f0.w);
    bfr.u[2] = pkbf(f1.x, f1.y); bfr.u[3] = pkbf(f1.z, f1.w);
    #pragma unroll
    for (int i = 0; i < 4; i++) {
      bf16x8 af = *reinterpret_cast<const bf16x8*>(POOL + (size_t)(i * 16 + fr) * DD + k0 + fg * 8);
      acc[i] = MFMA(af, bfr.v, acc[i], 0, 0, 0);
    }
  }
  float bs = bias[n];
  #pragma unroll
  for (int i = 0; i < 4; i++)
    #pragma unroll
    for (int r = 0; r < 4; r++)
      out[(size_t)(i * 16 + fg * 4 + r) * VV + n] = acc[i][r] + bs;
}

extern "C" void kernel_launch(void* const* d_in, const int* in_sizes, int n_in,
                              void* d_out, int out_size, void* d_ws, size_t ws_size,
                              hipStream_t stream) {
  const int*   tokens  = (const int*)d_in[0];
  const float* tok_emb = (const float*)d_in[2];
  const float* pos_emb = (const float*)d_in[3];
  const float* emb_g   = (const float*)d_in[4];
  const float* emb_b   = (const float*)d_in[5];
  const float* ln1_g   = (const float*)d_in[6];
  const float* ln1_b   = (const float*)d_in[7];
  const float* Wqkv    = (const float*)d_in[8];
  const float* bqkv    = (const float*)d_in[9];
  const float* Wo      = (const float*)d_in[10];
  const float* bo      = (const float*)d_in[11];
  const float* ln2_g   = (const float*)d_in[12];
  const float* ln2_b   = (const float*)d_in[13];
  const float* W1      = (const float*)d_in[14];
  const float* b1      = (const float*)d_in[15];
  const float* W2      = (const float*)d_in[16];
  const float* b2      = (const float*)d_in[17];
  const float* cls_W   = (const float*)d_in[22];
  const float* cls_b   = (const float*)d_in[23];

  char* ws = (char*)d_ws;
  float*    X    = (float*)ws;                         // 33,554,432 B
  ushort_t* QKV  = (ushort_t*)(ws + 33554432);         // 50,331,648 B (QKV [m][768] / FF1 [m][512])
  ushort_t* Hb   = (ushort_t*)(ws + 83886080);         // 16,777,216 B
  ushort_t* WB   = (ushort_t*)(ws + 100663296);        //  1,048,576 B per-layer weights bf16
  ushort_t* POOL = (ushort_t*)(ws + 101711872);        //     32,768 B
  int*      LEN  = (int*)(ws + 101744640);             //        256 B

  const int OFF_QKV = 0, OFF_WO = 196608, OFF_W1 = 262144, OFF_W2 = 393216;

  k_lens<<<BB, 256, 0, stream>>>(tokens, LEN);
  k_embed4<<<MM / 4, 256, 0, stream>>>(tokens, tok_emb, pos_emb, emb_g, emb_b, X);

  for (int e = 0; e < KK; e++) {
    k_cvtw<<<512, 256, 0, stream>>>(Wqkv + (size_t)e * 196608, Wo + (size_t)e * 65536,
                                    W1 + (size_t)e * 131072, W2 + (size_t)e * 131072, WB);
    k_ln4<<<MM / 4, 256, 0, stream>>>(X, ln1_g + e * DD, ln1_b + e * DD, LEN, (bf16*)Hb);
    k_mgemm<128, 256, 256, false, false, true><<<dim3(3, 256), 256, 0, stream>>>(
        Hb, WB + OFF_QKV, bqkv + e * 3 * DD, nullptr, QKV, LEN, 3 * DD);
    k_mattn6<<<dim3(4, HH, BB), 512, 0, stream>>>(QKV, LEN, Hb);
    k_mgemm<64, 256, 256, false, true, false><<<dim3(1, 512), 256, 0, stream>>>(
        Hb, WB + OFF_WO, bo + e * DD, X, X, LEN, DD);
    k_ln4<<<MM / 4, 256, 0, stream>>>(X, ln2_g + e * DD, ln2_b + e * DD, LEN, (bf16*)Hb);
    k_mgemm<128, 256, 256, true, false, true><<<dim3(2, 256), 256, 0, stream>>>(
        Hb, WB + OFF_W1, b1 + e * FF, nullptr, QKV, LEN, FF);
    k_mgemm<64, 256, 512, false, true, false><<<dim3(1, 512), 256, 0, stream>>>(
        QKV, WB + OFF_W2, b2 + e * DD, X, X, LEN, DD);
  }

  k_pool<<<BB, 256, 0, stream>>>(X, LEN, (bf16*)POOL);
  k_cls<<<dim3(VV / 128), 512, 0, stream>>>(POOL, cls_W, cls_b, (float*)d_out);
}

// Round 11
// 808.844 us; speedup vs baseline: 2.8798x; 1.0873x over previous
//
#include <hip/hip_runtime.h>
#include <hip/hip_bf16.h>

#define BB 64
#define LL 512
#define DD 256
#define VV 32000
#define KK 6
#define HH 4
#define FF 512
#define MM (BB * LL)

typedef __hip_bfloat16 bf16;
typedef unsigned short ushort_t;
typedef __attribute__((ext_vector_type(8))) __bf16 bf16x8;
typedef __attribute__((ext_vector_type(4))) float f32x4;
#define MFMA __builtin_amdgcn_mfma_f32_16x16x32_bf16

__device__ __forceinline__ ushort_t f2bfbits(float x) {
  return __builtin_bit_cast(unsigned short, (__bf16)x);
}
__device__ __forceinline__ unsigned pkbf(float lo, float hi) {
  return (unsigned)f2bfbits(lo) | ((unsigned)f2bfbits(hi) << 16);
}
union U8 { unsigned u[4]; bf16x8 v; };

// async global->LDS, 16B/lane; dest must be WAVE-UNIFORM base (HW adds lane*16)
__device__ __forceinline__ void gl_lds16(const ushort_t* g, ushort_t* l) {
  __builtin_amdgcn_global_load_lds(
      (const __attribute__((address_space(1))) unsigned int*)g,
      (__attribute__((address_space(3))) unsigned int*)l, 16, 0, 0);
}

__device__ __forceinline__ float blk_sum(float v, float* red) {
  #pragma unroll
  for (int o = 32; o > 0; o >>= 1) v += __shfl_down(v, o, 64);
  __syncthreads();
  if ((threadIdx.x & 63) == 0) red[threadIdx.x >> 6] = v;
  __syncthreads();
  return red[0] + red[1] + red[2] + red[3];
}

__global__ __launch_bounds__(256) void k_lens(const int* __restrict__ tokens, int* __restrict__ lens) {
  __shared__ float red[4];
  int b = blockIdx.x, t = threadIdx.x;
  float c = (tokens[b * LL + t] != 0 ? 1.f : 0.f) + (tokens[b * LL + 256 + t] != 0 ? 1.f : 0.f);
  float s = blk_sum(c, red);
  if (t == 0) lens[b] = (int)(s + 0.5f);
}

// LPT order: order[rank] = b, ranks by descending len (ties by index)
__global__ __launch_bounds__(64) void k_order(const int* __restrict__ lens, int* __restrict__ order) {
  int b = threadIdx.x;
  __shared__ int L[64];
  int len = lens[b];
  L[b] = len;
  __syncthreads();
  int rank = 0;
  for (int i = 0; i < 64; i++) {
    int li = L[i];
    if (li > len || (li == len && i < b)) rank++;
  }
  order[rank] = b;
}

// embedding + emb-LN -> X, then ln1[0] -> Hb (both rows wave-local)
__global__ __launch_bounds__(256) void k_embed4(const int* __restrict__ tokens,
                                                const float* __restrict__ tok_emb,
                                                const float* __restrict__ pos_emb,
                                                const float* __restrict__ g,
                                                const float* __restrict__ be,
                                                const float* __restrict__ g1,
                                                const float* __restrict__ b1,
                                                float* __restrict__ X,
                                                bf16* __restrict__ H) {
  int wid = threadIdx.x >> 6, lane = threadIdx.x & 63;
  int row = blockIdx.x * 4 + wid;
  int l = row & (LL - 1);
  int tok = tokens[row];
  float4 a = *reinterpret_cast<const float4*>(tok_emb + (size_t)tok * DD + lane * 4);
  float4 p = *reinterpret_cast<const float4*>(pos_emb + (size_t)l * DD + lane * 4);
  float4 v = {a.x + p.x, a.y + p.y, a.z + p.z, a.w + p.w};
  float s = v.x + v.y + v.z + v.w;
  float q = v.x * v.x + v.y * v.y + v.z * v.z + v.w * v.w;
  #pragma unroll
  for (int o = 32; o > 0; o >>= 1) { s += __shfl_xor(s, o, 64); q += __shfl_xor(q, o, 64); }
  float mu = s * (1.f / DD);
  float rstd = rsqrtf(q * (1.f / DD) - mu * mu + 1e-5f);
  float4 gv = *reinterpret_cast<const float4*>(g + lane * 4);
  float4 bv = *reinterpret_cast<const float4*>(be + lane * 4);
  float4 o4 = {(v.x - mu) * rstd * gv.x + bv.x, (v.y - mu) * rstd * gv.y + bv.y,
               (v.z - mu) * rstd * gv.z + bv.z, (v.w - mu) * rstd * gv.w + bv.w};
  *reinterpret_cast<float4*>(X + (size_t)row * DD + lane * 4) = o4;
  // fused ln1[0]
  float s2 = o4.x + o4.y + o4.z + o4.w;
  float q2 = o4.x * o4.x + o4.y * o4.y + o4.z * o4.z + o4.w * o4.w;
  #pragma unroll
  for (int o = 32; o > 0; o >>= 1) { s2 += __shfl_xor(s2, o, 64); q2 += __shfl_xor(q2, o, 64); }
  float mu2 = s2 * (1.f / DD);
  float rstd2 = rsqrtf(q2 * (1.f / DD) - mu2 * mu2 + 1e-5f);
  float4 g1v = *reinterpret_cast<const float4*>(g1 + lane * 4);
  float4 b1v = *reinterpret_cast<const float4*>(b1 + lane * 4);
  ushort4 h4;
  h4.x = f2bfbits((o4.x - mu2) * rstd2 * g1v.x + b1v.x);
  h4.y = f2bfbits((o4.y - mu2) * rstd2 * g1v.y + b1v.y);
  h4.z = f2bfbits((o4.z - mu2) * rstd2 * g1v.z + b1v.z);
  h4.w = f2bfbits((o4.w - mu2) * rstd2 * g1v.w + b1v.w);
  *reinterpret_cast<ushort4*>((ushort_t*)H + (size_t)row * DD + lane * 4) = h4;
}

__global__ __launch_bounds__(256) void k_cvtw(const float* __restrict__ w0, const float* __restrict__ w1,
                                              const float* __restrict__ w2, const float* __restrict__ w3,
                                              ushort_t* __restrict__ d) {
  int i = (blockIdx.x * 256 + threadIdx.x) * 4;
  const float* s; int off;
  if (i < 196608)      { s = w0; off = i; }
  else if (i < 262144) { s = w1; off = i - 196608; }
  else if (i < 393216) { s = w2; off = i - 262144; }
  else                 { s = w3; off = i - 393216; }
  float4 v = *reinterpret_cast<const float4*>(s + off);
  ushort4 o;
  o.x = f2bfbits(v.x); o.y = f2bfbits(v.y); o.z = f2bfbits(v.z); o.w = f2bfbits(v.w);
  *reinterpret_cast<ushort4*>(d + i) = o;
}

// -------- MFMA GEMM: MT x NT tile, BK=32, 4 waves, triple-buffer + counted vmcnt --------
// FUSELN (requires MT=64, NT=256=Ndim): epilogue computes per-row LayerNorm and
// writes both X (f32, outp) and Hb (bf16, Hout).
template <int MT, int NT, int KD, bool GELU, bool RES, bool OUTBF16, bool FUSELN>
__global__ __launch_bounds__(256) void k_mgemm(const ushort_t* __restrict__ A,
                                               const ushort_t* __restrict__ Wb,
                                               const float* __restrict__ bias,
                                               const float* __restrict__ res,
                                               void* __restrict__ outp,
                                               ushort_t* __restrict__ Hout,
                                               const float* __restrict__ lng,
                                               const float* __restrict__ lnb,
                                               const int* __restrict__ lens,
                                               int Ndim) {
  constexpr int JF = (MT == 128) ? (NT / 32) : (NT / 64);
  constexpr int AR = MT / 64, BR = NT / 64;
  constexpr int L = AR + BR;
  constexpr int NK = KD / 32;
  int n0 = blockIdx.x * NT, m0 = blockIdx.y * MT;
  if ((m0 & (LL - 1)) >= lens[m0 >> 9]) return;
  __shared__ __align__(16) ushort_t As[3][MT * 32];
  __shared__ __align__(16) ushort_t Bs[3][NT * 32];
  int t = threadIdx.x, lane = t & 63, w = t >> 6;
  int wr = (MT == 128) ? (w >> 1) * 64 : 0;
  int wc = (MT == 128) ? (w & 1) * (NT / 2) : w * (NT / 4);
  int fr = lane & 15, fg = lane >> 4;

  int ca = lane & 3;
  const ushort_t* gA[AR];
  #pragma unroll
  for (int ra = 0; ra < AR; ra++) {
    int row = ra * 64 + (t >> 2);
    gA[ra] = A + (size_t)(m0 + row) * KD + ((ca ^ ((row >> 1) & 3)) << 3);
  }
  const ushort_t* gB[BR];
  #pragma unroll
  for (int rb = 0; rb < BR; rb++) {
    int row = rb * 64 + (t >> 2);
    gB[rb] = Wb + (size_t)(n0 + row) * KD + ((ca ^ ((row >> 1) & 3)) << 3);
  }

  f32x4 acc[4][JF];
  #pragma unroll
  for (int i = 0; i < 4; i++)
    #pragma unroll
    for (int j = 0; j < JF; j++) acc[i][j] = (f32x4){0.f, 0.f, 0.f, 0.f};

  #define STAGE(bi, koff) { \
    _Pragma("unroll") for (int ra = 0; ra < AR; ra++) gl_lds16(gA[ra] + (koff), &As[bi][ra * 2048 + w * 512]); \
    _Pragma("unroll") for (int rb = 0; rb < BR; rb++) gl_lds16(gB[rb] + (koff), &Bs[bi][rb * 2048 + w * 512]); }

  STAGE(0, 0);
  #pragma unroll
  for (int kt = 0; kt < NK; kt++) {
    int cur = kt % 3;
    if (kt + 1 < NK) {
      STAGE((kt + 1) % 3, (kt + 1) * 32);
      asm volatile("s_waitcnt vmcnt(%0)" :: "n"(L) : "memory");
    } else {
      asm volatile("s_waitcnt vmcnt(0)" ::: "memory");
    }
    __builtin_amdgcn_s_barrier();
    __builtin_amdgcn_sched_barrier(0);
    bf16x8 af[4], bfr[JF];
    #pragma unroll
    for (int i = 0; i < 4; i++) {
      int row = wr + i * 16 + fr;
      af[i] = *reinterpret_cast<const bf16x8*>(&As[cur][row * 32 + ((fg ^ ((row >> 1) & 3)) << 3)]);
    }
    #pragma unroll
    for (int j = 0; j < JF; j++) {
      int row = wc + j * 16 + fr;
      bfr[j] = *reinterpret_cast<const bf16x8*>(&Bs[cur][row * 32 + ((fg ^ ((row >> 1) & 3)) << 3)]);
    }
    #pragma unroll
    for (int i = 0; i < 4; i++)
      #pragma unroll
      for (int j = 0; j < JF; j++)
        acc[i][j] = MFMA(af[i], bfr[j], acc[i][j], 0, 0, 0);
  }
  #undef STAGE

  if constexpr (!FUSELN) {
    #pragma unroll
    for (int i = 0; i < 4; i++) {
      int mbase = m0 + wr + i * 16 + fg * 4;
      #pragma unroll
      for (int j = 0; j < JF; j++) {
        int n = n0 + wc + j * 16 + fr;
        float bs = bias[n];
        #pragma unroll
        for (int r = 0; r < 4; r++) {
          int m = mbase + r;
          float v = acc[i][j][r] + bs;
          if (RES) v += res[(size_t)m * Ndim + n];
          if (GELU) v = 0.5f * v * (1.f + erff(v * 0.70710678118f));
          if (OUTBF16) ((ushort_t*)outp)[(size_t)m * Ndim + n] = f2bfbits(v);
          else         ((float*)outp)[(size_t)m * Ndim + n] = v;
        }
      }
    }
  } else {
    // MT=64, NT=256=Ndim: block holds complete rows -> fused LayerNorm
    __shared__ float redS[4][64], redQ[4][64], lnmv[64], lnrv[64];
    float rs[4][4], rq[4][4];
    #pragma unroll
    for (int i = 0; i < 4; i++)
      #pragma unroll
      for (int r = 0; r < 4; r++) { rs[i][r] = 0.f; rq[i][r] = 0.f; }
    #pragma unroll
    for (int i = 0; i < 4; i++) {
      #pragma unroll
      for (int j = 0; j < 4; j++) {
        int n = wc + j * 16 + fr;
        float bs = bias[n];
        #pragma unroll
        for (int r = 0; r < 4; r++) {
          int m = m0 + i * 16 + fg * 4 + r;
          float v = acc[i][j][r] + bs;
          if (RES) v += res[(size_t)m * DD + n];
          acc[i][j][r] = v;
          ((float*)outp)[(size_t)m * DD + n] = v;
          rs[i][r] += v; rq[i][r] += v * v;
        }
      }
    }
    #pragma unroll
    for (int i = 0; i < 4; i++)
      #pragma unroll
      for (int r = 0; r < 4; r++) {
        float s = rs[i][r], q = rq[i][r];
        s += __shfl_xor(s, 1, 64); q += __shfl_xor(q, 1, 64);
        s += __shfl_xor(s, 2, 64); q += __shfl_xor(q, 2, 64);
        s += __shfl_xor(s, 4, 64); q += __shfl_xor(q, 4, 64);
        s += __shfl_xor(s, 8, 64); q += __shfl_xor(q, 8, 64);
        if (fr == 0) {
          redS[w][i * 16 + fg * 4 + r] = s;
          redQ[w][i * 16 + fg * 4 + r] = q;
        }
      }
    __syncthreads();
    if (t < 64) {
      float s = redS[0][t] + redS[1][t] + redS[2][t] + redS[3][t];
      float q = redQ[0][t] + redQ[1][t] + redQ[2][t] + redQ[3][t];
      float mu = s * (1.f / DD);
      lnmv[t] = mu;
      lnrv[t] = rsqrtf(q * (1.f / DD) - mu * mu + 1e-5f);
    }
    __syncthreads();
    #pragma unroll
    for (int i = 0; i < 4; i++) {
      #pragma unroll
      for (int j = 0; j < 4; j++) {
        int n = wc + j * 16 + fr;
        float gv = lng[n], bv = lnb[n];
        #pragma unroll
        for (int r = 0; r < 4; r++) {
          int rl = i * 16 + fg * 4 + r;
          float h = (acc[i][j][r] - lnmv[rl]) * lnrv[rl] * gv + bv;
          Hout[(size_t)(m0 + rl) * DD + n] = f2bfbits(h);
        }
      }
    }
  }
}

// -------- MFMA flash attention v7: LPT order, setprio, uniform tail-split --------
__global__ __launch_bounds__(512) void k_mattn7(const ushort_t* __restrict__ QKV,
                                                const int* __restrict__ lens,
                                                const int* __restrict__ order,
                                                ushort_t* __restrict__ O) {
  int b = order[blockIdx.z], h = blockIdx.y;
  int len = lens[b];
  int q0 = blockIdx.x * 128;
  if (q0 >= len) return;
  int t = threadIdx.x, lane = t & 63, w = t >> 6;
  int fr = lane & 15, fg = lane >> 4;
  __shared__ __align__(16) ushort_t Kh[8192];   // [128 k][64 d], chunk ^= (k&7)
  __shared__ __align__(16) ushort_t Vh[8192];   // [64 d][128 k], chunk ^= S(d)&7

  const ushort_t* base = QKV + (size_t)b * LL * 768;
  int qw = q0 + w * 16;
  bool qact = qw < len;
  int q = qw + fr;

  const ushort_t* qp = base + (size_t)q * 768 + h * 64 + fg * 8;
  bf16x8 qf0 = *reinterpret_cast<const bf16x8*>(qp);
  bf16x8 qf1 = *reinterpret_cast<const bf16x8*>(qp + 32);

  const float SC = 0.125f * 1.44269504f;
  f32x4 ot[4];
  #pragma unroll
  for (int df = 0; df < 4; df++) ot[df] = (f32x4){0.f, 0.f, 0.f, 0.f};
  float m_run = -1e30f, lsum = 0.f;

  for (int kb = 0; kb < len; kb += 128) {
    if (kb) __syncthreads();
    int lim = min(128, len - kb);
    #pragma unroll
    for (int rr = 0; rr < 2; rr++) {
      if (rr * 64 >= lim) break;
      int krow = rr * 64 + w * 8 + (lane >> 3);
      int gk = kb + krow; if (gk > len - 1) gk = len - 1;
      int ch = lane & 7;
      const ushort_t* src = base + (size_t)gk * 768 + 256 + h * 64 + ((ch ^ (krow & 7)) << 3);
      gl_lds16(src, &Kh[rr * 4096 + w * 512]);
    }
    #pragma unroll
    for (int it = 0; it < 2; it++) {
      if (it * 64 >= lim) break;
      int c = it * 512 + t;
      int k = c >> 3, dg = c & 7;
      int gk = kb + k; if (gk > len - 1) gk = len - 1;
      uint4 vv = *reinterpret_cast<const uint4*>(base + (size_t)gk * 768 + 512 + h * 64 + dg * 8);
      unsigned uu[4] = {vv.x, vv.y, vv.z, vv.w};
      #pragma unroll
      for (int j = 0; j < 4; j++) {
        int d0 = dg * 8 + j * 2, d1 = d0 + 1;
        int s0 = (d0 ^ (d0 >> 3)) & 7, s1 = (d1 ^ (d1 >> 3)) & 7;
        Vh[d0 * 128 + (((k >> 3) ^ s0) << 3) + (k & 7)] = (ushort_t)(uu[j] & 0xffff);
        Vh[d1 * 128 + (((k >> 3) ^ s1) << 3) + (k & 7)] = (ushort_t)(uu[j] >> 16);
      }
    }
    __syncthreads();

    if (qact) {
      for (int kt = 0; kt < lim; kt += 64) {
        f32x4 s[4];
        __builtin_amdgcn_s_setprio(1);
        #pragma unroll
        for (int f = 0; f < 4; f++) {
          s[f] = (f32x4){0.f, 0.f, 0.f, 0.f};
          int krow = kt + f * 16 + fr;
          const ushort_t* kp0 = &Kh[krow * 64 + ((fg ^ (krow & 7)) << 3)];
          const ushort_t* kp1 = &Kh[krow * 64 + (((4 + fg) ^ (krow & 7)) << 3)];
          s[f] = MFMA(*reinterpret_cast<const bf16x8*>(kp0), qf0, s[f], 0, 0, 0);
          s[f] = MFMA(*reinterpret_cast<const bf16x8*>(kp1), qf1, s[f], 0, 0, 0);
        }
        __builtin_amdgcn_s_setprio(0);
        if (lim - kt >= 64) {           // full tile: no masking
          #pragma unroll
          for (int f = 0; f < 4; f++)
            #pragma unroll
            for (int r = 0; r < 4; r++) s[f][r] *= SC;
        } else {
          int rem = lim - kt;
          #pragma unroll
          for (int f = 0; f < 4; f++)
            #pragma unroll
            for (int r = 0; r < 4; r++)
              s[f][r] = (f * 16 + fg * 4 + r < rem) ? s[f][r] * SC : -1e30f;
        }
        float tm = -1e30f;
        #pragma unroll
        for (int f = 0; f < 4; f++)
          #pragma unroll
          for (int r = 0; r < 4; r++) tm = fmaxf(tm, s[f][r]);
        tm = fmaxf(tm, __shfl_xor(tm, 16, 64));
        tm = fmaxf(tm, __shfl_xor(tm, 32, 64));
        bool grow = tm > m_run;
        if (__any(grow)) {
          float m_new = grow ? tm : m_run;
          float corr = exp2f(m_run - m_new);
          lsum *= corr;
          #pragma unroll
          for (int df = 0; df < 4; df++)
            #pragma unroll
            for (int r = 0; r < 4; r++) ot[df][r] *= corr;
          m_run = m_new;
        }
        float ps = 0.f;
        #pragma unroll
        for (int f = 0; f < 4; f++)
          #pragma unroll
          for (int r = 0; r < 4; r++) {
            float p = exp2f(s[f][r] - m_run);
            s[f][r] = p; ps += p;
          }
        ps += __shfl_xor(ps, 16, 64);
        ps += __shfl_xor(ps, 32, 64);
        lsum += ps;
        #pragma unroll
        for (int st = 0; st < 2; st++) {
          int fA = st * 2, fB = fA + 1;
          unsigned a0 = pkbf(s[fA][0], s[fA][1]), a1 = pkbf(s[fA][2], s[fA][3]);
          unsigned b0 = pkbf(s[fB][0], s[fB][1]), b1 = pkbf(s[fB][2], s[fB][3]);
          int sA = ((fg & 1) * 2) * 16 + fr;
          int sB = sA + 16;
          unsigned wa0 = __shfl(a0, sA, 64), wb0 = __shfl(b0, sA, 64);
          unsigned wa1 = __shfl(a1, sA, 64), wb1 = __shfl(b1, sA, 64);
          unsigned wa2 = __shfl(a0, sB, 64), wb2 = __shfl(b0, sB, 64);
          unsigned wa3 = __shfl(a1, sB, 64), wb3 = __shfl(b1, sB, 64);
          bool lo = fg < 2;
          U8 pf;
          pf.u[0] = lo ? wa0 : wb0; pf.u[1] = lo ? wa1 : wb1;
          pf.u[2] = lo ? wa2 : wb2; pf.u[3] = lo ? wa3 : wb3;
          int cb = (kt >> 3) + st * 4 + fg;
          __builtin_amdgcn_s_setprio(1);
          #pragma unroll
          for (int df = 0; df < 4; df++) {
            int d = df * 16 + fr;
            int sd = (d ^ (d >> 3)) & 7;
            const ushort_t* vp = &Vh[d * 128 + ((cb ^ sd) << 3)];
            ot[df] = MFMA(*reinterpret_cast<const bf16x8*>(vp), pf.v, ot[df], 0, 0, 0);
          }
          __builtin_amdgcn_s_setprio(0);
        }
      }
    }
  }

  if (q < len) {
    float linv = 1.f / lsum;
    #pragma unroll
    for (int df = 0; df < 4; df++) {
      ushort4 ov;
      ov.x = f2bfbits(ot[df][0] * linv);
      ov.y = f2bfbits(ot[df][1] * linv);
      ov.z = f2bfbits(ot[df][2] * linv);
      ov.w = f2bfbits(ot[df][3] * linv);
      *reinterpret_cast<ushort4*>(O + (size_t)(b * LL + q) * DD + h * 64 + df * 16 + fg * 4) = ov;
    }
  }
}

// -------- final attention pooling --------
__global__ __launch_bounds__(256) void k_pool(const float* __restrict__ X,
                                              const int* __restrict__ lens,
                                              bf16* __restrict__ pooled) {
  __shared__ float red[4];
  __shared__ float qs[DD];
  __shared__ float sc[LL];
  int b = blockIdx.x, t = threadIdx.x;
  int len = lens[b];
  const float* Xb = X + (size_t)b * LL * DD;
  qs[t] = Xb[(size_t)(len - 1) * DD + t];
  __syncthreads();
  for (int l = t; l < LL; l += 256) {
    float s = -1e30f;
    if (l < len) {
      const float4* xr = reinterpret_cast<const float4*>(Xb + (size_t)l * DD);
      const float4* qq = reinterpret_cast<const float4*>(qs);
      float a0 = 0, a1 = 0, a2 = 0, a3 = 0;
      for (int k4 = 0; k4 < 64; k4++) {
        float4 xv = xr[k4], qv = qq[k4];
        a0 += xv.x * qv.x; a1 += xv.y * qv.y; a2 += xv.z * qv.z; a3 += xv.w * qv.w;
      }
      s = (a0 + a1) + (a2 + a3);
    }
    sc[l] = s;
  }
  __syncthreads();
  float mx = fmaxf(sc[t], sc[t + 256]);
  #pragma unroll
  for (int off = 32; off > 0; off >>= 1) mx = fmaxf(mx, __shfl_down(mx, off, 64));
  __syncthreads();
  if ((t & 63) == 0) red[t >> 6] = mx;
  __syncthreads();
  mx = fmaxf(fmaxf(red[0], red[1]), fmaxf(red[2], red[3]));
  float e0 = (t < len) ? __expf(sc[t] - mx) : 0.f;
  float e1 = (t + 256 < len) ? __expf(sc[t + 256] - mx) : 0.f;
  float ssum = blk_sum(e0 + e1, red);
  float inv = 1.f / ssum;
  __syncthreads();
  sc[t] = e0 * inv; sc[t + 256] = e1 * inv;
  __syncthreads();
  float acc = 0.f;
  for (int l = 0; l < len; l++) acc += sc[l] * Xb[(size_t)l * DD + t];
  pooled[b * DD + t] = __float2bfloat16(acc);
}

// -------- classifier --------
__global__ __launch_bounds__(512) void k_cls(const ushort_t* __restrict__ POOL,
                                             const float* __restrict__ W,
                                             const float* __restrict__ bias,
                                             float* __restrict__ out) {
  int t = threadIdx.x, lane = t & 63, w = t >> 6;
  int fr = lane & 15, fg = lane >> 4;
  int n = blockIdx.x * 128 + w * 16 + fr;
  const float* wp = W + (size_t)n * DD + fg * 8;
  f32x4 acc[4];
  #pragma unroll
  for (int i = 0; i < 4; i++) acc[i] = (f32x4){0.f, 0.f, 0.f, 0.f};
  for (int k0 = 0; k0 < DD; k0 += 32) {
    float4 f0 = *reinterpret_cast<const float4*>(wp + k0);
    float4 f1 = *reinterpret_cast<const float4*>(wp + k0 + 4);
    U8 bfr;
    bfr.u[0] = pkbf(f0.x, f0.y); bfr.u[1] = pkbf(f0.z, f0.w);
    bfr.u[2] = pkbf(f1.x, f1.y); bfr.u[3] = pkbf(f1.z, f1.w);
    #pragma unroll
    for (int i = 0; i < 4; i++) {
      bf16x8 af = *reinterpret_cast<const bf16x8*>(POOL + (size_t)(i * 16 + fr) * DD + k0 + fg * 8);
      acc[i] = MFMA(af, bfr.v, acc[i], 0, 0, 0);
    }
  }
  float bs = bias[n];
  #pragma unroll
  for (int i = 0; i < 4; i++)
    #pragma unroll
    for (int r = 0; r < 4; r++)
      out[(size_t)(i * 16 + fg * 4 + r) * VV + n] = acc[i][r] + bs;
}

extern "C" void kernel_launch(void* const* d_in, const int* in_sizes, int n_in,
                              void* d_out, int out_size, void* d_ws, size_t ws_size,
                              hipStream_t stream) {
  const int*   tokens  = (const int*)d_in[0];
  const float* tok_emb = (const float*)d_in[2];
  const float* pos_emb = (const float*)d_in[3];
  const float* emb_g   = (const float*)d_in[4];
  const float* emb_b   = (const float*)d_in[5];
  const float* ln1_g   = (const float*)d_in[6];
  const float* ln1_b   = (const float*)d_in[7];
  const float* Wqkv    = (const float*)d_in[8];
  const float* bqkv    = (const float*)d_in[9];
  const float* Wo      = (const float*)d_in[10];
  const float* bo      = (const float*)d_in[11];
  const float* ln2_g   = (const float*)d_in[12];
  const float* ln2_b   = (const float*)d_in[13];
  const float* W1      = (const float*)d_in[14];
  const float* b1      = (const float*)d_in[15];
  const float* W2      = (const float*)d_in[16];
  const float* b2      = (const float*)d_in[17];
  const float* cls_W   = (const float*)d_in[22];
  const float* cls_b   = (const float*)d_in[23];

  char* ws = (char*)d_ws;
  float*    X    = (float*)ws;                         // 33,554,432 B
  ushort_t* QKV  = (ushort_t*)(ws + 33554432);         // 50,331,648 B (QKV [m][768] / FF1 [m][512])
  ushort_t* Hb   = (ushort_t*)(ws + 83886080);         // 16,777,216 B
  ushort_t* WB   = (ushort_t*)(ws + 100663296);        //  1,048,576 B per-layer weights bf16
  ushort_t* POOL = (ushort_t*)(ws + 101711872);        //     32,768 B
  int*      LEN  = (int*)(ws + 101744640);             //        256 B
  int*      ORD  = (int*)(ws + 101744896);             //        256 B

  const int OFF_QKV = 0, OFF_WO = 196608, OFF_W1 = 262144, OFF_W2 = 393216;

  k_lens<<<BB, 256, 0, stream>>>(tokens, LEN);
  k_order<<<1, 64, 0, stream>>>(LEN, ORD);
  k_embed4<<<MM / 4, 256, 0, stream>>>(tokens, tok_emb, pos_emb, emb_g, emb_b,
                                       ln1_g, ln1_b, X, (bf16*)Hb);

  for (int e = 0; e < KK; e++) {
    k_cvtw<<<512, 256, 0, stream>>>(Wqkv + (size_t)e * 196608, Wo + (size_t)e * 65536,
                                    W1 + (size_t)e * 131072, W2 + (size_t)e * 131072, WB);
    k_mgemm<128, 256, 256, false, false, true, false><<<dim3(3, 256), 256, 0, stream>>>(
        Hb, WB + OFF_QKV, bqkv + e * 3 * DD, nullptr, QKV, nullptr, nullptr, nullptr, LEN, 3 * DD);
    k_mattn7<<<dim3(4, HH, BB), 512, 0, stream>>>(QKV, LEN, ORD, Hb);
    // Wo GEMM + residual + fused ln2[e] -> X, Hb
    k_mgemm<64, 256, 256, false, true, false, true><<<dim3(1, 512), 256, 0, stream>>>(
        Hb, WB + OFF_WO, bo + e * DD, X, X, Hb, ln2_g + e * DD, ln2_b + e * DD, LEN, DD);
    k_mgemm<128, 256, 256, true, false, true, false><<<dim3(2, 256), 256, 0, stream>>>(
        Hb, WB + OFF_W1, b1 + e * FF, nullptr, QKV, nullptr, nullptr, nullptr, LEN, FF);
    if (e < KK - 1) {
      // FF2 + residual + fused ln1[e+1] -> X, Hb
      k_mgemm<64, 256, 512, false, true, false, true><<<dim3(1, 512), 256, 0, stream>>>(
          QKV, WB + OFF_W2, b2 + e * DD, X, X, Hb,
          ln1_g + (e + 1) * DD, ln1_b + (e + 1) * DD, LEN, DD);
    } else {
      k_mgemm<64, 256, 512, false, true, false, false><<<dim3(1, 512), 256, 0, stream>>>(
          QKV, WB + OFF_W2, b2 + e * DD, X, X, nullptr, nullptr, nullptr, LEN, DD);
    }
  }

  k_pool<<<BB, 256, 0, stream>>>(X, LEN, (bf16*)POOL);
  k_cls<<<dim3(VV / 128), 512, 0, stream>>>(POOL, cls_W, cls_b, (float*)d_out);
}